// Round 1
// baseline (158.267 us; speedup 1.0000x reference)
//
#include <hip/hip_runtime.h>
#include <hip/hip_bf16.h>

typedef short bf16x8 __attribute__((ext_vector_type(8)));
typedef float f32x4 __attribute__((ext_vector_type(4)));

#define HID 128
#define NRAD 6

static __device__ __forceinline__ unsigned short f2bf(float f) {
    union { float f; unsigned u; } v; v.f = f;
    unsigned r = v.u + 0x7FFFu + ((v.u >> 16) & 1u);
    return (unsigned short)(r >> 16);
}

// ---------------------------------------------------------------------------
// Precompute kernel:
//   P1[v][n] = sum_k emb[v][k] * w_lin[k][n]        + b_lin[n]   (v in 0..94)
//   P2[v][n] = sum_k emb[v][k] * w_lin[128+k][n]
//   Wt[n][k] = (bf16) w_lin[256+k][n]      (W3 transposed, bf16)
// grid = 318 blocks x 128 threads: blocks 0..94 -> P1, 95..189 -> P2,
// 190..317 -> one k-row of Wt each.
// ---------------------------------------------------------------------------
__global__ void precompute_kernel(const float* __restrict__ emb,
                                  const float* __restrict__ w_lin,
                                  const float* __restrict__ b_lin,
                                  float* __restrict__ P1,
                                  float* __restrict__ P2,
                                  unsigned short* __restrict__ Wt) {
    const int b = blockIdx.x;
    const int t = threadIdx.x; // 0..127 = output column n
    if (b < 190) {
        const int v = (b < 95) ? b : b - 95;
        const float* W = w_lin + (b < 95 ? 0 : HID * HID);
        float acc = (b < 95) ? b_lin[t] : 0.0f;
        #pragma unroll 4
        for (int k = 0; k < HID; ++k)
            acc = fmaf(emb[v * HID + k], W[k * HID + t], acc);
        (b < 95 ? P1 : P2)[v * HID + t] = acc;
    } else {
        const int kr = b - 190; // 0..127
        Wt[t * HID + kr] = f2bf(w_lin[(2 * HID + kr) * HID + t]);
    }
}

// ---------------------------------------------------------------------------
// Main edge kernel: 64 edges per block, 256 threads (4 waves).
//   r = swish(rbf @ w_rbf + b_rbf)  -> bf16 in LDS (XOR-swizzled rows)
//   y = r @ W3 via mfma_f32_16x16x32_bf16 (W3^T bf16 staged in LDS, swizzled)
//   out = swish(y + P1[x[i]] + P2[x[j]])
// ---------------------------------------------------------------------------
__global__ __launch_bounds__(256, 3) void edge_kernel(
    const float* __restrict__ rbf, const int* __restrict__ ei,
    const int* __restrict__ ej, const int* __restrict__ x,
    const float* __restrict__ w_rbf, const float* __restrict__ b_rbf,
    const float* __restrict__ P1, const float* __restrict__ P2,
    const unsigned short* __restrict__ Wt,
    float* __restrict__ out, int E)
{
    __shared__ float s_wrbf[NRAD * HID];          // 3 KB
    __shared__ int s_xi[64], s_xj[64];            // 0.5 KB
    __shared__ unsigned short sA[64 * HID];       // 16 KB (swizzled rows of 256 B)
    __shared__ unsigned short sB[HID * HID];      // 32 KB (W3^T, swizzled)

    const int t = threadIdx.x;
    const int base = blockIdx.x * 64;

    // --- stage w_rbf ---
    for (int idx = t; idx < NRAD * HID; idx += 256) s_wrbf[idx] = w_rbf[idx];

    // --- stage gathered embedding-row ids: xi = x[i[e]], xj = x[j[e]] ---
    if (t < 64) {
        int e = min(base + t, E - 1);
        s_xi[t] = x[ei[e]];
    } else if (t < 128) {
        int e = min(base + (t - 64), E - 1);
        s_xj[t - 64] = x[ej[e]];
    }

    // --- stage W3^T (bf16) into sB with XOR swizzle ---
    {
        const uint4* g = (const uint4*)Wt;        // 16 chunks of 16 B per row
        #pragma unroll
        for (int q = 0; q < 8; ++q) {
            int gi = q * 256 + t;                 // 0..2047, coalesced
            int n = gi >> 4, cc = gi & 15;
            uint4 v = g[gi];
            int off = n * 256 + ((cc * 16) ^ ((n & 7) << 4));
            *(uint4*)((char*)sB + off) = v;
        }
    }
    __syncthreads();

    // --- compute A tile: r = swish(rbf @ w_rbf + b_rbf), bf16, swizzled ---
    {
        const int row = t & 63;
        const int e = base + row;
        float rq[NRAD];
        #pragma unroll
        for (int q = 0; q < NRAD; ++q)
            rq[q] = (e < E) ? rbf[(size_t)e * NRAD + q] : 0.0f;
        const int g0 = (t >> 6) * 4;
        #pragma unroll
        for (int gg = 0; gg < 4; ++gg) {
            const int g = g0 + gg;                // col group of 8
            unsigned short pk[8];
            #pragma unroll
            for (int u = 0; u < 8; ++u) {
                const int n = g * 8 + u;
                float z = b_rbf[n];
                #pragma unroll
                for (int q = 0; q < NRAD; ++q)
                    z = fmaf(rq[q], s_wrbf[q * HID + n], z);
                float rr = z / (1.0f + __expf(-z));
                pk[u] = f2bf(rr);
            }
            const int off = row * 256 + ((g * 16) ^ ((row & 7) << 4));
            *(uint4*)((char*)sA + off) = *(const uint4*)pk;
        }
    }
    __syncthreads();

    // --- MFMA: each wave computes 16 edges x 128 cols ---
    const int w = t >> 6;
    const int l = t & 63;
    const int lr = l & 15, lg = l >> 4;

    f32x4 acc[8];
    #pragma unroll
    for (int f = 0; f < 8; ++f) acc[f] = (f32x4){0.f, 0.f, 0.f, 0.f};

    #pragma unroll
    for (int kk = 0; kk < 4; ++kk) {
        const int colb = kk * 64 + lg * 16;       // byte offset within row
        const int rowA = w * 16 + lr;
        bf16x8 a = *(const bf16x8*)((const char*)sA +
                      rowA * 256 + (colb ^ ((rowA & 7) << 4)));
        #pragma unroll
        for (int f = 0; f < 8; ++f) {
            const int rowB = f * 16 + lr;
            bf16x8 bb = *(const bf16x8*)((const char*)sB +
                          rowB * 256 + (colb ^ ((rowB & 7) << 4)));
            acc[f] = __builtin_amdgcn_mfma_f32_16x16x32_bf16(a, bb, acc[f], 0, 0, 0);
        }
    }

    // --- epilogue: add gathered table rows, swish, store ---
    const float* p1p[4];
    const float* p2p[4];
    long ebase[4];
    bool valid[4];
    #pragma unroll
    for (int r = 0; r < 4; ++r) {
        const int row = w * 16 + lg * 4 + r;      // C/D: row = (lane>>4)*4 + reg
        const int e = base + row;
        valid[r] = (e < E);
        p1p[r] = P1 + s_xi[row] * HID;
        p2p[r] = P2 + s_xj[row] * HID;
        ebase[r] = (long)e * HID;
    }
    #pragma unroll
    for (int f = 0; f < 8; ++f) {
        const int n = f * 16 + lr;                // C/D: col = lane&15
        #pragma unroll
        for (int r = 0; r < 4; ++r) {
            if (valid[r]) {
                float v = acc[f][r] + p1p[r][n] + p2p[r][n];
                out[ebase[r] + n] = v / (1.0f + __expf(-v));
            }
        }
    }
}

extern "C" void kernel_launch(void* const* d_in, const int* in_sizes, int n_in,
                              void* d_out, int out_size, void* d_ws, size_t ws_size,
                              hipStream_t stream) {
    const int*   x     = (const int*)  d_in[0];
    const float* rbf   = (const float*)d_in[1];
    const int*   ei    = (const int*)  d_in[2];
    const int*   ej    = (const int*)  d_in[3];
    const float* emb   = (const float*)d_in[4];
    const float* w_rbf = (const float*)d_in[5];
    const float* b_rbf = (const float*)d_in[6];
    const float* w_lin = (const float*)d_in[7];
    const float* b_lin = (const float*)d_in[8];
    float* out = (float*)d_out;
    const int E = in_sizes[2];

    // workspace layout (all 256-B aligned): P1 (95*128 f32), P2, Wt (128x128 bf16)
    float* P1 = (float*)d_ws;
    float* P2 = (float*)((char*)d_ws + 49152);
    unsigned short* Wt = (unsigned short*)((char*)d_ws + 98304);

    hipLaunchKernelGGL(precompute_kernel, dim3(318), dim3(128), 0, stream,
                       emb, w_lin, b_lin, P1, P2, Wt);

    const int nblk = (E + 63) / 64;
    hipLaunchKernelGGL(edge_kernel, dim3(nblk), dim3(256), 0, stream,
                       rbf, ei, ej, x, w_rbf, b_rbf, P1, P2, Wt, out, E);
}